// Round 3
// baseline (601.894 us; speedup 1.0000x reference)
//
#include <hip/hip_runtime.h>

// FAVOR+ attention, B=4 L=4096 D=1024 H=16 d=64 m=256, fp32 in/out.
// MFMA via v_mfma_f32_16x16x32_bf16 with split-bf16 (hi+lo, 3 products) fp32
// emulation. stab=0 (verified equivalent). R3: occupancy round —
//  kv: grid 1024 = (bh x ch x m-half), LDS 28.7KB, launch_bounds(512,8)
//      -> 4 blocks/CU (was 2, grid-capped).
//  out: 32-row tiles (grid 8192), qp LDS 34.6KB, denominator via VALU dot
//      (frees MFMA ct=4 tile, balances stage B to 1 tile/wave).
//  prep grid 128, fragk grid 256 (+f32 ksum output).
// Pipeline: prep (W frags + zero kvx) -> kv (proj+exp, k'^T@[V|1] via MFMA,
// atomic partial sums) -> fragk (kvx -> hi/lo B-frags + ksum) -> out.

typedef unsigned short u16;
typedef __attribute__((ext_vector_type(8))) short s8v;   // 8 bf16 (4 VGPR)
typedef __attribute__((ext_vector_type(4))) float f4v;   // C/D frag

#define NL 4096
#define ND 1024
#define HDIM 64
#define NM 256

#define SCALE 0.17677669529663687f  // 1024^-0.25
#define RSQM 0.0625f                // 256^-0.5
#define FEPS 1e-4f
#define ECLAMP 80.0f

#define MFMA16(a, b, c) __builtin_amdgcn_mfma_f32_16x16x32_bf16((a), (b), (c), 0, 0, 0)

__device__ __forceinline__ u16 f2bf(float x) {  // RNE bf16 (prep/fragk only)
  unsigned u = __float_as_uint(x);
  u += 0x7FFFu + ((u >> 16) & 1u);
  return (u16)(u >> 16);
}
__device__ __forceinline__ float bf2f(u16 b) {
  return __uint_as_float(((unsigned)b) << 16);
}
// Truncation split: hi = top 16 bits; residual trunc error ~2^-17 relative.
__device__ __forceinline__ u16 bhi(float x) {
  return (u16)(__float_as_uint(x) >> 16);
}
__device__ __forceinline__ float bhif(float x) {
  return __uint_as_float(__float_as_uint(x) & 0xFFFF0000u);
}

// A-frag pair (hi/lo, trunc) from 8 scaled floats; accumulate sum of squares.
__device__ __forceinline__ void mk2t(const float4& a, const float4& b, float sc,
                                     s8v& hi, s8v& lo, float& ss) {
  float f[8] = {a.x * sc, a.y * sc, a.z * sc, a.w * sc,
                b.x * sc, b.y * sc, b.z * sc, b.w * sc};
#pragma unroll
  for (int e = 0; e < 8; e++) {
    ss = fmaf(f[e], f[e], ss);
    hi[e] = (short)bhi(f[e]);
    lo[e] = (short)bhi(f[e] - bhif(f[e]));
  }
}
// Same without the norm (queries don't need it).
__device__ __forceinline__ void mk2q(const float4& a, const float4& b, float sc,
                                     s8v& hi, s8v& lo) {
  float f[8] = {a.x * sc, a.y * sc, a.z * sc, a.w * sc,
                b.x * sc, b.y * sc, b.z * sc, b.w * sc};
#pragma unroll
  for (int e = 0; e < 8; e++) {
    hi[e] = (short)bhi(f[e]);
    lo[e] = (short)bhi(f[e] - bhif(f[e]));
  }
}

// W B-fragments: layout [kk(2)][mt(16)][lane(64)][e(8)].
// B[k][j]: j = mt*16 + (lane&15), k = kk*32 + (lane>>4)*8 + e, value = W[j][k].
// Also zeroes the kvx accumulator (re-zeroed every launch; atomics add into it).
__global__ void prep_kernel(const float* __restrict__ wp, u16* __restrict__ WfH,
                            u16* __restrict__ WfL, float* __restrict__ kvx) {
  const int idx = blockIdx.x * 512 + threadIdx.x;  // grid 128 -> 0..65535
  if (idx < 16384) {
    const int e = idx & 7, ln = (idx >> 3) & 63, mt = (idx >> 9) & 15, kk = idx >> 13;
    const int m = mt * 16 + (ln & 15);
    const int d = kk * 32 + ((ln >> 4) << 3) + e;
    const float x = wp[m * HDIM + d];
    const u16 hh = f2bf(x);
    WfH[idx] = hh;
    WfL[idx] = f2bf(x - bf2f(hh));
  }
  for (int i = idx; i < 64 * 256 * 80; i += 65536) kvx[i] = 0.f;
}

// Grid 1024 = mh(2) x bh(64) x ch(8); 512 threads = 8 waves. Block: 512 rows,
// 16 iters of 32; computes the 128-feature half mh. Stage A: proj via MFMA
// (A-frags from global K, row norms via shfl), exp -> k' hi/lo to LDS kp[m][l].
// V frags built once per tile (wave w: ct=w&3, hi/lo=w>>2). Stage B (1 m-tile
// per wave): kv[128][80] += k'^T @ [V | 1]; ksum lands in column 64.
// Block index: mh in the high bit so the K-sharing pair lands on one XCD.
__global__ __launch_bounds__(512, 8) void kv_kernel(
    const float* __restrict__ kg, const float* __restrict__ vg,
    const u16* __restrict__ WfH, const u16* __restrict__ WfL,
    float* __restrict__ kvx) {
  const int bx = blockIdx.x;
  const int mh = bx >> 9, bh = (bx >> 3) & 63, ch = bx & 7;
  const int b = bh >> 4, h = bh & 15;
  const int tid = threadIdx.x, lane = tid & 63, w = tid >> 6;
  const int l15 = lane & 15, g = lane >> 4;

  __shared__ __align__(16) u16 kpH[128][40];   // [m_local][l], stride 80 B
  __shared__ __align__(16) u16 kpL[128][40];
  __shared__ __align__(16) u16 VfH[4][64][8];  // V B-frags, per ct
  __shared__ __align__(16) u16 VfL[4][64][8];

  const int rt = w & 1, mg = w >> 1;    // stage A: rows rt*16.., tiles mg*2+mi
  const int vct = w & 3, vhl = w >> 2;  // V-frag duty: column tile, hi-or-lo

  f4v zero4 = {0.f, 0.f, 0.f, 0.f};
  f4v acc[5];
#pragma unroll
  for (int j = 0; j < 5; j++) acc[j] = zero4;

  s8v oneh = {0, 0, 0, 0, 0, 0, 0, 0};  // ones-column B-frag (col 64 only)
  if (l15 == 0) {
#pragma unroll
    for (int e = 0; e < 8; e++) oneh[e] = (short)0x3F80;
  }

  for (int it = 0; it < 16; it++) {
    const int rbase = ch * 512 + it * 32;
    // V scalar loads (wave-specific fragment); issue early, consume late.
    const float* vb =
        vg + (size_t)(b * NL + rbase + 8 * g) * ND + h * HDIM + vct * 16 + l15;
    float vx[8];
#pragma unroll
    for (int e = 0; e < 8; e++) vx[e] = vb[(size_t)e * ND];
    // K A-frags straight from global (16-lane x 32B chunks; L1 merges)
    const float* kb = kg + (size_t)(b * NL + rbase + rt * 16 + l15) * ND + h * HDIM;
    const float4 ka0 = *(const float4*)(kb + g * 8);
    const float4 ka1 = *(const float4*)(kb + g * 8 + 4);
    const float4 ka2 = *(const float4*)(kb + 32 + g * 8);
    const float4 ka3 = *(const float4*)(kb + 32 + g * 8 + 4);
    s8v a0h, a0l, a1h, a1l;
    float ss = 0.f;
    mk2t(ka0, ka1, SCALE, a0h, a0l, ss);
    mk2t(ka2, ka3, SCALE, a1h, a1l, ss);
    ss += __shfl_xor(ss, 16);
    ss += __shfl_xor(ss, 32);  // full ||k^row||^2, row = rt*16 + l15
    const float cneg = -0.5f * ss;
    float ccr[4];
#pragma unroll
    for (int r = 0; r < 4; r++) ccr[r] = __shfl(cneg, 4 * g + r);

    // this wave's V fragment (trunc split)
    s8v vf;
    if (vhl == 0) {
#pragma unroll
      for (int e = 0; e < 8; e++) vf[e] = (short)bhi(vx[e]);
    } else {
#pragma unroll
      for (int e = 0; e < 8; e++) vf[e] = (short)bhi(vx[e] - bhif(vx[e]));
    }

    // LICM-breaker: keep W-frag loads inside the loop (hoisting = 64 VGPRs)
    int itz = it;
    asm volatile("" : "+v"(itz));
    const u16* WfHp = WfH + (itz & 0x7FFF0000);  // == WfH at runtime
    const u16* WfLp = WfL + (itz & 0x7FFF0000);

    u16 hs[2][4], ls[2][4];
#pragma unroll
    for (int mi = 0; mi < 2; mi++) {
      const int mt = mh * 8 + mg * 2 + mi;  // global m-tile
      const s8v b0h = *(const s8v*)(WfHp + (size_t)(mt * 64 + lane) * 8);
      const s8v b0l = *(const s8v*)(WfLp + (size_t)(mt * 64 + lane) * 8);
      const s8v b1h = *(const s8v*)(WfHp + (size_t)((16 + mt) * 64 + lane) * 8);
      const s8v b1l = *(const s8v*)(WfLp + (size_t)((16 + mt) * 64 + lane) * 8);
      f4v p = zero4;
      p = MFMA16(a0h, b0h, p);
      p = MFMA16(a1h, b1h, p);
      p = MFMA16(a0h, b0l, p);
      p = MFMA16(a1h, b1l, p);
      p = MFMA16(a0l, b0h, p);
      p = MFMA16(a1l, b1h, p);
#pragma unroll
      for (int r = 0; r < 4; r++) {
        const float arg = fminf(p[r] + ccr[r], ECLAMP);
        const float kv_ = RSQM * __expf(arg) + (RSQM * FEPS);
        hs[mi][r] = bhi(kv_);
        ls[mi][r] = bhi(kv_ - bhif(kv_));
      }
    }
    __syncthreads();  // previous iteration's stage-B readers are done
#pragma unroll
    for (int mi = 0; mi < 2; mi++) {
      const int ml = (mg * 2 + mi) * 16 + l15;  // local m row
      *(ushort4*)&kpH[ml][rt * 16 + 4 * g] =
          make_ushort4(hs[mi][0], hs[mi][1], hs[mi][2], hs[mi][3]);
      *(ushort4*)&kpL[ml][rt * 16 + 4 * g] =
          make_ushort4(ls[mi][0], ls[mi][1], ls[mi][2], ls[mi][3]);
    }
    {  // publish V fragment: one conflict-free b128 per thread
      u16(*vdst)[64][8] = vhl ? VfL : VfH;
      *(s8v*)&vdst[vct][lane][0] = vf;
    }
    __syncthreads();

    // stage B: wave w owns local m-tile w; A-frags one ds_read_b128 each
    const s8v A0h = *(const s8v*)&kpH[w * 16 + l15][8 * g];
    const s8v A0l = *(const s8v*)&kpL[w * 16 + l15][8 * g];
#pragma unroll
    for (int ct = 0; ct < 4; ct++) {
      const s8v vh = *(const s8v*)&VfH[ct][lane][0];
      const s8v vl = *(const s8v*)&VfL[ct][lane][0];
      acc[ct] = MFMA16(A0h, vh, acc[ct]);
      acc[ct] = MFMA16(A0h, vl, acc[ct]);
      acc[ct] = MFMA16(A0l, vh, acc[ct]);
    }
    acc[4] = MFMA16(A0h, oneh, acc[4]);  // ksum column (ones, lo = 0)
    acc[4] = MFMA16(A0l, oneh, acc[4]);
  }

  float* kvb = kvx + (size_t)bh * (256 * 80);
#pragma unroll
  for (int ct = 0; ct < 5; ct++)
#pragma unroll
    for (int r = 0; r < 4; r++) {
      if (ct == 4 && l15 != 0) continue;  // cols 65..79 are exact zeros
      const int m = mh * 128 + w * 16 + 4 * g + r;
      const int c = ct * 16 + l15;
      atomicAdd(&kvb[m * 80 + c], acc[ct][r]);
    }
}

// kvx (summed) -> hi/lo B-fragments for ct 0..3, layout
// [bh][kk(8)][ct(4)][lane(64)][e(8)], plus f32 ksum from column 64.
// B[k][j]: k = kk*32 + (lane>>4)*8 + e (m axis), j = ct*16 + (lane&15).
__global__ __launch_bounds__(512) void fragk_kernel(const float* __restrict__ kvx,
                                                    u16* __restrict__ kvfH,
                                                    u16* __restrict__ kvfL,
                                                    float* __restrict__ ksg) {
  const int bh = blockIdx.x >> 2, qq = blockIdx.x & 3;  // grid 256
  const float* kb = kvx + (size_t)bh * (256 * 80);
  for (int f = qq * 4096 + threadIdx.x; f < (qq + 1) * 4096; f += 512) {
    const int kk = f >> 11, ct = (f >> 9) & 3, r2 = f & 511;
    const int ln = r2 >> 3, e = r2 & 7;
    const int m = kk * 32 + ((ln >> 4) << 3) + e;
    const int c = ct * 16 + (ln & 15);
    const float x = kb[m * 80 + c];
    const u16 hh = f2bf(x);
    kvfH[(size_t)bh * 16384 + f] = hh;
    kvfL[(size_t)bh * 16384 + f] = f2bf(x - bf2f(hh));
  }
  if (qq == 0 && threadIdx.x < 256)
    ksg[(size_t)bh * 256 + threadIdx.x] = kb[threadIdx.x * 80 + 64];
}

// Grid 8192 = (bh 64) x (32-row L-tile 128); 512 threads = 8 waves.
// Stage A: q' = RSQM*exp(proj)+RSQM*eps -> hi/lo into qp[l][m] (stride 264,
// 16B-aligned rows). Denominator: wave-local fp32 dot q'.ksum (rows 4w+g).
// Stage B: one 16x16 output tile per wave (rt2 = w>>2, ctile = w&3).
__global__ __launch_bounds__(512, 8) void out_kernel(
    const float* __restrict__ qg, const u16* __restrict__ WfH,
    const u16* __restrict__ WfL, const u16* __restrict__ kvfH,
    const u16* __restrict__ kvfL, const float* __restrict__ ksg,
    float* __restrict__ outp) {
  const int bh = blockIdx.x >> 7, lt = blockIdx.x & 127;
  const int b = bh >> 4, h = bh & 15;
  const int tid = threadIdx.x, lane = tid & 63, w = tid >> 6;
  const int l15 = lane & 15, g = lane >> 4;

  __shared__ __align__(16) u16 qpH[32][264];  // [l][m], stride 528 B
  __shared__ __align__(16) u16 qpL[32][264];
  __shared__ float ksl[256];
  __shared__ float dinv[32];

  const int rt = w & 1, mhg = w >> 1;  // stage A: rows rt*16.., tiles mhg*4..

  if (tid < 256) ksl[tid] = ksg[(size_t)bh * 256 + tid];

  {  // ---- stage A ----
    const float* qb = qg + (size_t)(b * NL + lt * 32 + rt * 16 + l15) * ND + h * HDIM;
    const float4 qa0 = *(const float4*)(qb + g * 8);
    const float4 qa1 = *(const float4*)(qb + g * 8 + 4);
    const float4 qa2 = *(const float4*)(qb + 32 + g * 8);
    const float4 qa3 = *(const float4*)(qb + 32 + g * 8 + 4);
    s8v a0h, a0l, a1h, a1l;
    mk2q(qa0, qa1, SCALE, a0h, a0l);
    mk2q(qa2, qa3, SCALE, a1h, a1l);
    f4v zero4 = {0.f, 0.f, 0.f, 0.f};
#pragma unroll
    for (int mi = 0; mi < 4; mi++) {
      const int mt = mhg * 4 + mi;
      const s8v b0h = *(const s8v*)(WfH + (size_t)(mt * 64 + lane) * 8);
      const s8v b0l = *(const s8v*)(WfL + (size_t)(mt * 64 + lane) * 8);
      const s8v b1h = *(const s8v*)(WfH + (size_t)((16 + mt) * 64 + lane) * 8);
      const s8v b1l = *(const s8v*)(WfL + (size_t)((16 + mt) * 64 + lane) * 8);
      f4v p = zero4;
      p = MFMA16(a0h, b0h, p);
      p = MFMA16(a1h, b1h, p);
      p = MFMA16(a0h, b0l, p);
      p = MFMA16(a1h, b1l, p);
      p = MFMA16(a0l, b0h, p);
      p = MFMA16(a1l, b1h, p);
#pragma unroll
      for (int r = 0; r < 4; r++) {
        // queries: stab = h cancels exactly -> q' = RSQM*exp(proj) + RSQM*eps
        const float arg = fminf(p[r], ECLAMP);
        const float qv = RSQM * __expf(arg) + (RSQM * FEPS);
        qpH[rt * 16 + 4 * g + r][mt * 16 + l15] = bhi(qv);
        qpL[rt * 16 + 4 * g + r][mt * 16 + l15] = bhi(qv - bhif(qv));
      }
    }
  }
  __syncthreads();

  {  // ---- denominator ---- wave w owns rows 4w..4w+3 (row = 4w+g, seg = l15)
    const int row = 4 * w + g;
    const s8v qh0 = *(const s8v*)&qpH[row][l15 * 16];
    const s8v qh1 = *(const s8v*)&qpH[row][l15 * 16 + 8];
    const s8v ql0 = *(const s8v*)&qpL[row][l15 * 16];
    const s8v ql1 = *(const s8v*)&qpL[row][l15 * 16 + 8];
    float dsum = 0.f;
#pragma unroll
    for (int i = 0; i < 8; i++) {
      const float q0 = bf2f((u16)qh0[i]) + bf2f((u16)ql0[i]);
      const float q1 = bf2f((u16)qh1[i]) + bf2f((u16)ql1[i]);
      dsum = fmaf(q0, ksl[l15 * 16 + i], dsum);
      dsum = fmaf(q1, ksl[l15 * 16 + 8 + i], dsum);
    }
    dsum += __shfl_xor(dsum, 1);
    dsum += __shfl_xor(dsum, 2);
    dsum += __shfl_xor(dsum, 4);
    dsum += __shfl_xor(dsum, 8);
    if (l15 == 0) {
      float d = dsum;
      if (fabsf(d) <= FEPS) d += 2.0f * FEPS;
      dinv[row] = 1.0f / d;
    }
  }

  // ---- stage B ---- one tile per wave
  const int rt2 = w >> 2, ctile = w & 3;
  f4v o0 = {0.f, 0.f, 0.f, 0.f};
  const size_t fb = (size_t)bh * 16384;
#pragma unroll
  for (int kk = 0; kk < 8; kk++) {
    const s8v A2h = *(const s8v*)&qpH[rt2 * 16 + l15][kk * 32 + 8 * g];
    const s8v A2l = *(const s8v*)&qpL[rt2 * 16 + l15][kk * 32 + 8 * g];
    const size_t bA = fb + (size_t)((kk * 4 + ctile) * 64 + lane) * 8;
    const s8v BAh = *(const s8v*)(kvfH + bA);
    const s8v BAl = *(const s8v*)(kvfL + bA);
    o0 = MFMA16(A2h, BAh, o0);
    o0 = MFMA16(A2h, BAl, o0);
    o0 = MFMA16(A2l, BAh, o0);
  }
  __syncthreads();  // dinv ready
  {
    float* ob = outp + (size_t)(b * NL + lt * 32) * ND + h * HDIM;
#pragma unroll
    for (int r = 0; r < 4; r++) {
      const int row = rt2 * 16 + 4 * g + r;
      ob[(size_t)row * ND + ctile * 16 + l15] = o0[r] * dinv[row];
    }
  }
}

extern "C" void kernel_launch(void* const* d_in, const int* in_sizes, int n_in,
                              void* d_out, int out_size, void* d_ws, size_t ws_size,
                              hipStream_t stream) {
  const float* q = (const float*)d_in[0];
  const float* k = (const float*)d_in[1];
  const float* v = (const float*)d_in[2];
  const float* w = (const float*)d_in[3];
  float* out = (float*)d_out;

  // workspace: WfH 32KB | WfL 32KB | kvx 5.24MB | kvfH 2.10MB | kvfL 2.10MB
  // | ksg 64KB  (total ~9.6 MB)
  u16* WfH = (u16*)d_ws;
  u16* WfL = WfH + 16384;
  float* kvx = (float*)((char*)d_ws + 65536);
  u16* kvfH = (u16*)((char*)d_ws + 65536 + (size_t)64 * 256 * 80 * 4);
  u16* kvfL = kvfH + (size_t)64 * 16384;
  float* ksg = (float*)((char*)kvfL + (size_t)64 * 16384 * 2);

  prep_kernel<<<128, 512, 0, stream>>>(w, WfH, WfL, kvx);
  kv_kernel<<<1024, 512, 0, stream>>>(k, v, WfH, WfL, kvx);
  fragk_kernel<<<256, 512, 0, stream>>>(kvx, kvfH, kvfL, ksg);
  out_kernel<<<8192, 512, 0, stream>>>(q, WfH, WfL, kvfH, kvfL, ksg, out);
}

// Round 4
// 411.379 us; speedup vs baseline: 1.4631x; 1.4631x over previous
//
#include <hip/hip_runtime.h>

// FAVOR+ attention, B=4 L=4096 D=1024 H=16 d=64 m=256, fp32 in/out.
// MFMA via v_mfma_f32_16x16x32_bf16 with split-bf16 (hi+lo, 3 products) fp32
// emulation. stab=0 (verified equivalent).
// R4: R3 structure, but launch_bounds back to (512,4) — R3's (512,8) squeezed
// the unified VGPR+AGPR budget to 64 (arch VGPRs -> 32) and spilled to scratch
// (FETCH 70->697 MB). (512,4) is the R2-proven spill-free envelope.
//  kv: grid 1024 = mh(2) x bh(64) x ch(8), LDS 28.7KB.
//  out: 32-row tiles (grid 8192), qp LDS 34.6KB, denominator via VALU dot.
//  prep grid 128, fragk grid 256 (+f32 ksum output).

typedef unsigned short u16;
typedef __attribute__((ext_vector_type(8))) short s8v;   // 8 bf16 (4 VGPR)
typedef __attribute__((ext_vector_type(4))) float f4v;   // C/D frag

#define NL 4096
#define ND 1024
#define HDIM 64
#define NM 256

#define SCALE 0.17677669529663687f  // 1024^-0.25
#define RSQM 0.0625f                // 256^-0.5
#define FEPS 1e-4f
#define ECLAMP 80.0f

#define MFMA16(a, b, c) __builtin_amdgcn_mfma_f32_16x16x32_bf16((a), (b), (c), 0, 0, 0)

__device__ __forceinline__ u16 f2bf(float x) {  // RNE bf16 (prep/fragk only)
  unsigned u = __float_as_uint(x);
  u += 0x7FFFu + ((u >> 16) & 1u);
  return (u16)(u >> 16);
}
__device__ __forceinline__ float bf2f(u16 b) {
  return __uint_as_float(((unsigned)b) << 16);
}
// Truncation split: hi = top 16 bits; residual trunc error ~2^-17 relative.
__device__ __forceinline__ u16 bhi(float x) {
  return (u16)(__float_as_uint(x) >> 16);
}
__device__ __forceinline__ float bhif(float x) {
  return __uint_as_float(__float_as_uint(x) & 0xFFFF0000u);
}

// A-frag pair (hi/lo, trunc) from 8 scaled floats; accumulate sum of squares.
__device__ __forceinline__ void mk2t(const float4& a, const float4& b, float sc,
                                     s8v& hi, s8v& lo, float& ss) {
  float f[8] = {a.x * sc, a.y * sc, a.z * sc, a.w * sc,
                b.x * sc, b.y * sc, b.z * sc, b.w * sc};
#pragma unroll
  for (int e = 0; e < 8; e++) {
    ss = fmaf(f[e], f[e], ss);
    hi[e] = (short)bhi(f[e]);
    lo[e] = (short)bhi(f[e] - bhif(f[e]));
  }
}
// Same without the norm (queries don't need it).
__device__ __forceinline__ void mk2q(const float4& a, const float4& b, float sc,
                                     s8v& hi, s8v& lo) {
  float f[8] = {a.x * sc, a.y * sc, a.z * sc, a.w * sc,
                b.x * sc, b.y * sc, b.z * sc, b.w * sc};
#pragma unroll
  for (int e = 0; e < 8; e++) {
    hi[e] = (short)bhi(f[e]);
    lo[e] = (short)bhi(f[e] - bhif(f[e]));
  }
}

// W B-fragments: layout [kk(2)][mt(16)][lane(64)][e(8)].
// B[k][j]: j = mt*16 + (lane&15), k = kk*32 + (lane>>4)*8 + e, value = W[j][k].
// Also zeroes the kvx accumulator (re-zeroed every launch; atomics add into it).
__global__ void prep_kernel(const float* __restrict__ wp, u16* __restrict__ WfH,
                            u16* __restrict__ WfL, float* __restrict__ kvx) {
  const int idx = blockIdx.x * 512 + threadIdx.x;  // grid 128 -> 0..65535
  if (idx < 16384) {
    const int e = idx & 7, ln = (idx >> 3) & 63, mt = (idx >> 9) & 15, kk = idx >> 13;
    const int m = mt * 16 + (ln & 15);
    const int d = kk * 32 + ((ln >> 4) << 3) + e;
    const float x = wp[m * HDIM + d];
    const u16 hh = f2bf(x);
    WfH[idx] = hh;
    WfL[idx] = f2bf(x - bf2f(hh));
  }
  for (int i = idx; i < 64 * 256 * 80; i += 65536) kvx[i] = 0.f;
}

// Grid 1024 = mh(2) x bh(64) x ch(8); 512 threads = 8 waves. Block: 512 rows,
// 16 iters of 32; computes the 128-feature half mh. Stage A: proj via MFMA
// (A-frags from global K, row norms via shfl), exp -> k' hi/lo to LDS kp[m][l].
// V frags built once per tile (wave w: ct=w&3, hi/lo=w>>2). Stage B (1 m-tile
// per wave): kv[128][80] += k'^T @ [V | 1]; ksum lands in column 64.
__global__ __launch_bounds__(512, 4) void kv_kernel(
    const float* __restrict__ kg, const float* __restrict__ vg,
    const u16* __restrict__ WfH, const u16* __restrict__ WfL,
    float* __restrict__ kvx) {
  const int bx = blockIdx.x;
  const int mh = bx >> 9, bh = (bx >> 3) & 63, ch = bx & 7;
  const int b = bh >> 4, h = bh & 15;
  const int tid = threadIdx.x, lane = tid & 63, w = tid >> 6;
  const int l15 = lane & 15, g = lane >> 4;

  __shared__ __align__(16) u16 kpH[128][40];   // [m_local][l], stride 80 B
  __shared__ __align__(16) u16 kpL[128][40];
  __shared__ __align__(16) u16 VfH[4][64][8];  // V B-frags, per ct
  __shared__ __align__(16) u16 VfL[4][64][8];

  const int rt = w & 1, mg = w >> 1;    // stage A: rows rt*16.., tiles mg*2+mi
  const int vct = w & 3, vhl = w >> 2;  // V-frag duty: column tile, hi-or-lo

  f4v zero4 = {0.f, 0.f, 0.f, 0.f};
  f4v acc[5];
#pragma unroll
  for (int j = 0; j < 5; j++) acc[j] = zero4;

  s8v oneh = {0, 0, 0, 0, 0, 0, 0, 0};  // ones-column B-frag (col 64 only)
  if (l15 == 0) {
#pragma unroll
    for (int e = 0; e < 8; e++) oneh[e] = (short)0x3F80;
  }

  for (int it = 0; it < 16; it++) {
    const int rbase = ch * 512 + it * 32;
    // V scalar loads (wave-specific fragment); issue early, consume late.
    const float* vb =
        vg + (size_t)(b * NL + rbase + 8 * g) * ND + h * HDIM + vct * 16 + l15;
    float vx[8];
#pragma unroll
    for (int e = 0; e < 8; e++) vx[e] = vb[(size_t)e * ND];
    // K A-frags straight from global (16-lane x 32B chunks; L1 merges)
    const float* kb = kg + (size_t)(b * NL + rbase + rt * 16 + l15) * ND + h * HDIM;
    const float4 ka0 = *(const float4*)(kb + g * 8);
    const float4 ka1 = *(const float4*)(kb + g * 8 + 4);
    const float4 ka2 = *(const float4*)(kb + 32 + g * 8);
    const float4 ka3 = *(const float4*)(kb + 32 + g * 8 + 4);
    s8v a0h, a0l, a1h, a1l;
    float ss = 0.f;
    mk2t(ka0, ka1, SCALE, a0h, a0l, ss);
    mk2t(ka2, ka3, SCALE, a1h, a1l, ss);
    ss += __shfl_xor(ss, 16);
    ss += __shfl_xor(ss, 32);  // full ||k^row||^2, row = rt*16 + l15
    const float cneg = -0.5f * ss;
    float ccr[4];
#pragma unroll
    for (int r = 0; r < 4; r++) ccr[r] = __shfl(cneg, 4 * g + r);

    // this wave's V fragment (trunc split)
    s8v vf;
    if (vhl == 0) {
#pragma unroll
      for (int e = 0; e < 8; e++) vf[e] = (short)bhi(vx[e]);
    } else {
#pragma unroll
      for (int e = 0; e < 8; e++) vf[e] = (short)bhi(vx[e] - bhif(vx[e]));
    }

    // LICM-breaker: keep W-frag loads inside the loop (hoisting = 64 VGPRs)
    int itz = it;
    asm volatile("" : "+v"(itz));
    const u16* WfHp = WfH + (itz & 0x7FFF0000);  // == WfH at runtime
    const u16* WfLp = WfL + (itz & 0x7FFF0000);

    u16 hs[2][4], ls[2][4];
#pragma unroll
    for (int mi = 0; mi < 2; mi++) {
      const int mt = mh * 8 + mg * 2 + mi;  // global m-tile
      const s8v b0h = *(const s8v*)(WfHp + (size_t)(mt * 64 + lane) * 8);
      const s8v b0l = *(const s8v*)(WfLp + (size_t)(mt * 64 + lane) * 8);
      const s8v b1h = *(const s8v*)(WfHp + (size_t)((16 + mt) * 64 + lane) * 8);
      const s8v b1l = *(const s8v*)(WfLp + (size_t)((16 + mt) * 64 + lane) * 8);
      f4v p = zero4;
      p = MFMA16(a0h, b0h, p);
      p = MFMA16(a1h, b1h, p);
      p = MFMA16(a0h, b0l, p);
      p = MFMA16(a1h, b1l, p);
      p = MFMA16(a0l, b0h, p);
      p = MFMA16(a1l, b1h, p);
#pragma unroll
      for (int r = 0; r < 4; r++) {
        const float arg = fminf(p[r] + ccr[r], ECLAMP);
        const float kv_ = RSQM * __expf(arg) + (RSQM * FEPS);
        hs[mi][r] = bhi(kv_);
        ls[mi][r] = bhi(kv_ - bhif(kv_));
      }
    }
    __syncthreads();  // previous iteration's stage-B readers are done
#pragma unroll
    for (int mi = 0; mi < 2; mi++) {
      const int ml = (mg * 2 + mi) * 16 + l15;  // local m row
      *(ushort4*)&kpH[ml][rt * 16 + 4 * g] =
          make_ushort4(hs[mi][0], hs[mi][1], hs[mi][2], hs[mi][3]);
      *(ushort4*)&kpL[ml][rt * 16 + 4 * g] =
          make_ushort4(ls[mi][0], ls[mi][1], ls[mi][2], ls[mi][3]);
    }
    {  // publish V fragment: one conflict-free b128 per thread
      u16(*vdst)[64][8] = vhl ? VfL : VfH;
      *(s8v*)&vdst[vct][lane][0] = vf;
    }
    __syncthreads();

    // stage B: wave w owns local m-tile w; A-frags one ds_read_b128 each
    const s8v A0h = *(const s8v*)&kpH[w * 16 + l15][8 * g];
    const s8v A0l = *(const s8v*)&kpL[w * 16 + l15][8 * g];
#pragma unroll
    for (int ct = 0; ct < 4; ct++) {
      const s8v vh = *(const s8v*)&VfH[ct][lane][0];
      const s8v vl = *(const s8v*)&VfL[ct][lane][0];
      acc[ct] = MFMA16(A0h, vh, acc[ct]);
      acc[ct] = MFMA16(A0h, vl, acc[ct]);
      acc[ct] = MFMA16(A0l, vh, acc[ct]);
    }
    acc[4] = MFMA16(A0h, oneh, acc[4]);  // ksum column (ones, lo = 0)
    acc[4] = MFMA16(A0l, oneh, acc[4]);
  }

  float* kvb = kvx + (size_t)bh * (256 * 80);
#pragma unroll
  for (int ct = 0; ct < 5; ct++)
#pragma unroll
    for (int r = 0; r < 4; r++) {
      if (ct == 4 && l15 != 0) continue;  // cols 65..79 are exact zeros
      const int m = mh * 128 + w * 16 + 4 * g + r;
      const int c = ct * 16 + l15;
      atomicAdd(&kvb[m * 80 + c], acc[ct][r]);
    }
}

// kvx (summed) -> hi/lo B-fragments for ct 0..3, layout
// [bh][kk(8)][ct(4)][lane(64)][e(8)], plus f32 ksum from column 64.
// B[k][j]: k = kk*32 + (lane>>4)*8 + e (m axis), j = ct*16 + (lane&15).
__global__ __launch_bounds__(512) void fragk_kernel(const float* __restrict__ kvx,
                                                    u16* __restrict__ kvfH,
                                                    u16* __restrict__ kvfL,
                                                    float* __restrict__ ksg) {
  const int bh = blockIdx.x >> 2, qq = blockIdx.x & 3;  // grid 256
  const float* kb = kvx + (size_t)bh * (256 * 80);
  for (int f = qq * 4096 + threadIdx.x; f < (qq + 1) * 4096; f += 512) {
    const int kk = f >> 11, ct = (f >> 9) & 3, r2 = f & 511;
    const int ln = r2 >> 3, e = r2 & 7;
    const int m = kk * 32 + ((ln >> 4) << 3) + e;
    const int c = ct * 16 + (ln & 15);
    const float x = kb[m * 80 + c];
    const u16 hh = f2bf(x);
    kvfH[(size_t)bh * 16384 + f] = hh;
    kvfL[(size_t)bh * 16384 + f] = f2bf(x - bf2f(hh));
  }
  if (qq == 0 && threadIdx.x < 256)
    ksg[(size_t)bh * 256 + threadIdx.x] = kb[threadIdx.x * 80 + 64];
}

// Grid 8192 = (bh 64) x (32-row L-tile 128); 512 threads = 8 waves.
// Stage A: q' = RSQM*exp(proj)+RSQM*eps -> hi/lo into qp[l][m] (stride 264,
// 16B-aligned rows). Denominator: wave-local fp32 dot q'.ksum (rows 4w+g).
// Stage B: one 16x16 output tile per wave (rt2 = w>>2, ctile = w&3).
__global__ __launch_bounds__(512, 4) void out_kernel(
    const float* __restrict__ qg, const u16* __restrict__ WfH,
    const u16* __restrict__ WfL, const u16* __restrict__ kvfH,
    const u16* __restrict__ kvfL, const float* __restrict__ ksg,
    float* __restrict__ outp) {
  const int bh = blockIdx.x >> 7, lt = blockIdx.x & 127;
  const int b = bh >> 4, h = bh & 15;
  const int tid = threadIdx.x, lane = tid & 63, w = tid >> 6;
  const int l15 = lane & 15, g = lane >> 4;

  __shared__ __align__(16) u16 qpH[32][264];  // [l][m], stride 528 B
  __shared__ __align__(16) u16 qpL[32][264];
  __shared__ float ksl[256];
  __shared__ float dinv[32];

  const int rt = w & 1, mhg = w >> 1;  // stage A: rows rt*16.., tiles mhg*4..

  if (tid < 256) ksl[tid] = ksg[(size_t)bh * 256 + tid];

  {  // ---- stage A ----
    const float* qb = qg + (size_t)(b * NL + lt * 32 + rt * 16 + l15) * ND + h * HDIM;
    const float4 qa0 = *(const float4*)(qb + g * 8);
    const float4 qa1 = *(const float4*)(qb + g * 8 + 4);
    const float4 qa2 = *(const float4*)(qb + 32 + g * 8);
    const float4 qa3 = *(const float4*)(qb + 32 + g * 8 + 4);
    s8v a0h, a0l, a1h, a1l;
    mk2q(qa0, qa1, SCALE, a0h, a0l);
    mk2q(qa2, qa3, SCALE, a1h, a1l);
    f4v zero4 = {0.f, 0.f, 0.f, 0.f};
#pragma unroll
    for (int mi = 0; mi < 4; mi++) {
      const int mt = mhg * 4 + mi;
      const s8v b0h = *(const s8v*)(WfH + (size_t)(mt * 64 + lane) * 8);
      const s8v b0l = *(const s8v*)(WfL + (size_t)(mt * 64 + lane) * 8);
      const s8v b1h = *(const s8v*)(WfH + (size_t)((16 + mt) * 64 + lane) * 8);
      const s8v b1l = *(const s8v*)(WfL + (size_t)((16 + mt) * 64 + lane) * 8);
      f4v p = zero4;
      p = MFMA16(a0h, b0h, p);
      p = MFMA16(a1h, b1h, p);
      p = MFMA16(a0h, b0l, p);
      p = MFMA16(a1h, b1l, p);
      p = MFMA16(a0l, b0h, p);
      p = MFMA16(a1l, b1h, p);
#pragma unroll
      for (int r = 0; r < 4; r++) {
        // queries: stab = h cancels exactly -> q' = RSQM*exp(proj) + RSQM*eps
        const float arg = fminf(p[r], ECLAMP);
        const float qv = RSQM * __expf(arg) + (RSQM * FEPS);
        qpH[rt * 16 + 4 * g + r][mt * 16 + l15] = bhi(qv);
        qpL[rt * 16 + 4 * g + r][mt * 16 + l15] = bhi(qv - bhif(qv));
      }
    }
  }
  __syncthreads();

  {  // ---- denominator ---- wave w owns rows 4w..4w+3 (row = 4w+g, seg = l15)
    const int row = 4 * w + g;
    const s8v qh0 = *(const s8v*)&qpH[row][l15 * 16];
    const s8v qh1 = *(const s8v*)&qpH[row][l15 * 16 + 8];
    const s8v ql0 = *(const s8v*)&qpL[row][l15 * 16];
    const s8v ql1 = *(const s8v*)&qpL[row][l15 * 16 + 8];
    float dsum = 0.f;
#pragma unroll
    for (int i = 0; i < 8; i++) {
      const float q0 = bf2f((u16)qh0[i]) + bf2f((u16)ql0[i]);
      const float q1 = bf2f((u16)qh1[i]) + bf2f((u16)ql1[i]);
      dsum = fmaf(q0, ksl[l15 * 16 + i], dsum);
      dsum = fmaf(q1, ksl[l15 * 16 + 8 + i], dsum);
    }
    dsum += __shfl_xor(dsum, 1);
    dsum += __shfl_xor(dsum, 2);
    dsum += __shfl_xor(dsum, 4);
    dsum += __shfl_xor(dsum, 8);
    if (l15 == 0) {
      float d = dsum;
      if (fabsf(d) <= FEPS) d += 2.0f * FEPS;
      dinv[row] = 1.0f / d;
    }
  }

  // ---- stage B ---- one tile per wave
  const int rt2 = w >> 2, ctile = w & 3;
  f4v o0 = {0.f, 0.f, 0.f, 0.f};
  const size_t fb = (size_t)bh * 16384;
#pragma unroll
  for (int kk = 0; kk < 8; kk++) {
    const s8v A2h = *(const s8v*)&qpH[rt2 * 16 + l15][kk * 32 + 8 * g];
    const s8v A2l = *(const s8v*)&qpL[rt2 * 16 + l15][kk * 32 + 8 * g];
    const size_t bA = fb + (size_t)((kk * 4 + ctile) * 64 + lane) * 8;
    const s8v BAh = *(const s8v*)(kvfH + bA);
    const s8v BAl = *(const s8v*)(kvfL + bA);
    o0 = MFMA16(A2h, BAh, o0);
    o0 = MFMA16(A2h, BAl, o0);
    o0 = MFMA16(A2l, BAh, o0);
  }
  __syncthreads();  // dinv ready
  {
    float* ob = outp + (size_t)(b * NL + lt * 32) * ND + h * HDIM;
#pragma unroll
    for (int r = 0; r < 4; r++) {
      const int row = rt2 * 16 + 4 * g + r;
      ob[(size_t)row * ND + ctile * 16 + l15] = o0[r] * dinv[row];
    }
  }
}

extern "C" void kernel_launch(void* const* d_in, const int* in_sizes, int n_in,
                              void* d_out, int out_size, void* d_ws, size_t ws_size,
                              hipStream_t stream) {
  const float* q = (const float*)d_in[0];
  const float* k = (const float*)d_in[1];
  const float* v = (const float*)d_in[2];
  const float* w = (const float*)d_in[3];
  float* out = (float*)d_out;

  // workspace: WfH 32KB | WfL 32KB | kvx 5.24MB | kvfH 2.10MB | kvfL 2.10MB
  // | ksg 64KB  (total ~9.6 MB)
  u16* WfH = (u16*)d_ws;
  u16* WfL = WfH + 16384;
  float* kvx = (float*)((char*)d_ws + 65536);
  u16* kvfH = (u16*)((char*)d_ws + 65536 + (size_t)64 * 256 * 80 * 4);
  u16* kvfL = kvfH + (size_t)64 * 16384;
  float* ksg = (float*)((char*)kvfL + (size_t)64 * 16384 * 2);

  prep_kernel<<<128, 512, 0, stream>>>(w, WfH, WfL, kvx);
  kv_kernel<<<1024, 512, 0, stream>>>(k, v, WfH, WfL, kvx);
  fragk_kernel<<<256, 512, 0, stream>>>(kvx, kvfH, kvfL, ksg);
  out_kernel<<<8192, 512, 0, stream>>>(q, WfH, WfL, kvfH, kvfL, ksg, out);
}